// Round 5
// baseline (515.834 us; speedup 1.0000x reference)
//
#include <hip/hip_runtime.h>

#define TPB   256
#define WPB   4                   // waves per block
#define WTILE 64                  // batches per tile: 64 * 96 B = 6 KB
#define SLOTS 3                   // per-wave LDS ring depth (issue 2 tiles ahead)
#define SLOT_GRAN (WTILE * 6)     // 384 float4 granules per slot
#define NB    512                 // 512 blocks * 4 waves = 2048 waves; 65536 tiles -> 32/wave

typedef float f32x4 __attribute__((ext_vector_type(4)));

// HBM -> LDS direct (no VGPR staging). LDS dest is wave-uniform base + lane*16.
// The per-lane GLOBAL address carries the swizzle: within each 1 KB (64-granule)
// window, lane l fetches granule sig(l) = (l&7)*8 | (l>>3)  (8x8 transpose).
// So LDS granule g holds data granule (g & ~63) | sig(g & 63); reading data
// granule d means LDS granule (d & ~63) | sig(d & 63)  (sig is an involution).
// Read pattern d = 6t+j: 6t mod 64 covers each even value exactly twice, and
// sig spreads them 8-lanes-per-bank-quad for every j -> conflict-free b128.
#define GLL16(g, l)  __builtin_amdgcn_global_load_lds(                        \
    (const __attribute__((address_space(1))) void*)(g),                       \
    (__attribute__((address_space(3))) void*)(l), 16, 0, 0)

__device__ __forceinline__ float group_loss(f32x4 a, f32x4 b, f32x4 c) {
    // vectors are (y,z,w) of each float4 (column 0 dropped)
    const float n0 = a.y * a.y + a.z * a.z + a.w * a.w;
    const float n1 = b.y * b.y + b.z * b.z + b.w * b.w;
    const float n2 = c.y * c.y + c.z * c.z + c.w * c.w;
    const float p01 = a.y * b.y + a.z * b.z + a.w * b.w;
    const float p02 = a.y * c.y + a.z * c.z + a.w * c.w;
    const float p12 = b.y * c.y + b.z * c.z + b.w * c.w;
    const float r0 = rsqrtf(n0), r1 = rsqrtf(n1), r2 = rsqrtf(n2);
    const float d01 = p01 * r0 * r1;
    const float d02 = p02 * r0 * r2;
    const float d12 = p12 * r1 * r2;
    // diagonal terms <u_i,u_i> - 1 are ~0 in fp32; contribute ~1e-14 to the mean. Skip.
    return 2.f * (d01 * d01 + d02 * d02 + d12 * d12);
}

__global__ __launch_bounds__(TPB) void reg_loss_k1(
    const f32x4* __restrict__ in, float* __restrict__ partial, int B)
{
    __shared__ f32x4 lds[WPB][SLOTS][SLOT_GRAN];   // 72 KB -> 2 blocks/CU
    __shared__ float wsum[WPB];
    const int t    = threadIdx.x;
    const int lane = t & 63;
    const int wid  = t >> 6;

    const int nTiles = B / WTILE;
    const int nWaves = gridDim.x * WPB;
    const int wgid   = blockIdx.x * WPB + wid;

    const int sig = ((lane & 7) << 3) | (lane >> 3);   // 8x8 transpose, involution

    f32x4* __restrict__ wl = &lds[wid][0][0];

    // tiles handled by this wave: tb = wgid + m*nWaves, m = 0..M-1
    int M = 0;
    if (wgid < nTiles) M = (nTiles - 1 - wgid) / nWaves + 1;

    auto issue = [&](int m, int s) {
        const f32x4* src = in + (size_t)(wgid + (size_t)m * nWaves) * (WTILE * 6);
        f32x4* dst = wl + s * SLOT_GRAN;
        #pragma unroll
        for (int k = 0; k < 6; ++k)
            GLL16(src + (k << 6) + sig, dst + (k << 6));   // 1 KB contiguous window
    };

    // prologue: 2 tiles in flight
    if (M > 0) issue(0, 0);
    if (M > 1) issue(1, 1);

    float acc = 0.f;
    int s = 0;
    for (int m = 0; m < M; ++m) {
        const int rem = M - 1 - m;
        if (rem >= 2) {
            int s2 = s + 2; if (s2 >= SLOTS) s2 -= SLOTS;
            issue(m + 2, s2);                               // overwrites slot computed at m-1
            asm volatile("s_waitcnt vmcnt(12)" ::: "memory");  // tile m's 6 loads done
        } else if (rem == 1) {
            asm volatile("s_waitcnt vmcnt(6)" ::: "memory");
        } else {
            asm volatile("s_waitcnt vmcnt(0)" ::: "memory");
        }

        const f32x4* q = wl + s * SLOT_GRAN;
        f32x4 r[6];
        #pragma unroll
        for (int j = 0; j < 6; ++j) {
            const int d  = lane * 6 + j;
            const int Lg = (d & ~63) | (((d & 7) << 3) | ((d & 63) >> 3));
            r[j] = q[Lg];                                   // conflict-free ds_read_b128
        }
        acc += group_loss(r[0], r[1], r[2]);
        acc += group_loss(r[3], r[4], r[5]);

        if (++s >= SLOTS) s = 0;
    }

    // tail (B % WTILE != 0) — direct loads, block 0 only (dead at B = 4.19e6)
    if (blockIdx.x == 0) {
        for (int b = (B / WTILE) * WTILE + t; b < B; b += TPB) {
            const f32x4* p = in + (size_t)b * 6;
            acc += group_loss(p[0], p[1], p[2]);
            acc += group_loss(p[3], p[4], p[5]);
        }
    }

    // wave (64-lane) reduce, then cross-wave via LDS (cold path)
    for (int off = 32; off > 0; off >>= 1)
        acc += __shfl_down(acc, off, 64);
    if (lane == 0) wsum[wid] = acc;
    __syncthreads();
    if (t == 0) {
        float sum = 0.f;
        #pragma unroll
        for (int w2 = 0; w2 < WPB; ++w2) sum += wsum[w2];
        partial[blockIdx.x] = sum;
    }
}

// Reduce partials -> mean (double accumulation, single block).
__global__ __launch_bounds__(TPB) void reg_loss_k2(
    const float* __restrict__ partial, float* __restrict__ out, int n, int B)
{
    __shared__ double wsum[TPB / 64];
    const int t = threadIdx.x;
    double s = 0.0;
    for (int i = t; i < n; i += TPB) s += (double)partial[i];
    for (int off = 32; off > 0; off >>= 1)
        s += __shfl_down(s, off, 64);
    if ((t & 63) == 0) wsum[t >> 6] = s;
    __syncthreads();
    if (t == 0) {
        double tot = 0.0;
        #pragma unroll
        for (int w = 0; w < TPB / 64; ++w) tot += wsum[w];
        out[0] = (float)(tot / (double)B);
    }
}

extern "C" void kernel_launch(void* const* d_in, const int* in_sizes, int n_in,
                              void* d_out, int out_size, void* d_ws, size_t ws_size,
                              hipStream_t stream) {
    const f32x4* in = (const f32x4*)d_in[0];
    const int B = in_sizes[0] / 24;            // (B, 6, 4) fp32
    float* partial = (float*)d_ws;

    int nb = NB;
    if ((size_t)nb * sizeof(float) > ws_size)
        nb = (int)(ws_size / sizeof(float));
    if (nb < 1) nb = 1;

    reg_loss_k1<<<nb, TPB, 0, stream>>>(in, partial, B);
    reg_loss_k2<<<1, TPB, 0, stream>>>(partial, (float*)d_out, nb, B);
}